// Round 17
// baseline (205.797 us; speedup 1.0000x reference)
//
#include <hip/hip_runtime.h>

constexpr int N_NODES = 50000;
constexpr int N_EDGES = 800000;
constexpr int NBINS   = 782;     // ceil(50000/64), 64 nodes per bin
constexpr int BINCAP  = 1536;    // mean 1024, sd 32 -> +16 sigma, never overflows
constexpr int XPAD    = 128;     // xb row stride in shorts (256 B, line-aligned)

typedef __attribute__((ext_vector_type(8))) short short8;
typedef __attribute__((ext_vector_type(8))) unsigned short ushort8;
typedef __attribute__((ext_vector_type(4))) float floatx4;

static __device__ __forceinline__ unsigned short f2bf(float f) {
    unsigned u = __float_as_uint(f);
    u += 0x7FFF + ((u >> 16) & 1);
    return (unsigned short)(u >> 16);
}
static __device__ __forceinline__ float bf2f(unsigned short s) {
    return __uint_as_float(((unsigned)s) << 16);
}

// ---------------- K_p: x fp32 -> bf16 (row-padded to 256B); W transpose->bf16;
// zero g and bin_cnt
__global__ __launch_bounds__(256) void k_prep(const float* __restrict__ x,
                                              unsigned short* __restrict__ xb,
                                              const float* __restrict__ Wrel,
                                              const float* __restrict__ Wroot,
                                              unsigned short* __restrict__ wt,
                                              float* __restrict__ g,
                                              int* __restrict__ bin_cnt) {
    int idx = blockIdx.x * 256 + threadIdx.x;
    if (idx < 49152) {                                  // Wt[n][k] = bf16(Wcat[k][n])
        int k = idx % 192;
        int n = idx / 192;
        float v = (k < 96) ? Wrel[k * 256 + n] : Wroot[(k - 96) * 256 + n];
        wt[idx] = f2bf(v);
    }
    if (idx < 16384) {
        reinterpret_cast<float4*>(g)[idx] = make_float4(0.f, 0.f, 0.f, 0.f);
    } else if (idx < 16384 + 196) {                     // 784 ints >= NBINS
        reinterpret_cast<int4*>(bin_cnt)[idx - 16384] = make_int4(0, 0, 0, 0);
    }
    if (idx >= N_NODES * 96 / 8) return;
    const float4* p = reinterpret_cast<const float4*>(x) + idx * 2;
    float4 u = p[0], v = p[1];
    short8 a;
    a[0] = (short)f2bf(u.x); a[1] = (short)f2bf(u.y);
    a[2] = (short)f2bf(u.z); a[3] = (short)f2bf(u.w);
    a[4] = (short)f2bf(v.x); a[5] = (short)f2bf(v.y);
    a[6] = (short)f2bf(v.z); a[7] = (short)f2bf(v.w);
    int row = idx / 12, c = idx - row * 12;
    *reinterpret_cast<short8*>(xb + row * XPAD + c * 8) = a;
}

// ---------------- binned fill, fixed-capacity bins (OOB-hardened)
__global__ __launch_bounds__(256) void k_fill_bin(const int* __restrict__ ei,
                                                  int* __restrict__ bin_cnt,
                                                  int* __restrict__ eb) {
    __shared__ int h[NBINS];
    __shared__ int gbase[NBINS];
    int t = threadIdx.x;
    for (int b = t; b < NBINS; b += 256) h[b] = 0;
    __syncthreads();
    int e0 = blockIdx.x * 6144;
#pragma unroll
    for (int i = 0; i < 24; i++) {
        int e = e0 + i * 256 + t;
        if (e < N_EDGES) atomicAdd(&h[ei[N_EDGES + e] >> 6], 1);
    }
    __syncthreads();
    for (int b = t; b < NBINS; b += 256) {
        int c = h[b];
        gbase[b] = c ? atomicAdd(&bin_cnt[b], c) : 0;
        h[b] = 0;
    }
    __syncthreads();
#pragma unroll
    for (int i = 0; i < 24; i++) {
        int e = e0 + i * 256 + t;
        if (e < N_EDGES) {
            int s = ei[e];
            int d = ei[N_EDGES + e];
            int bin = d >> 6;
            int p = gbase[bin] + atomicAdd(&h[bin], 1);
            if (p < BINCAP)                       // hardening: never write OOB
                eb[bin * BINCAP + p] = (s << 6) | (d & 63);
        }
    }
}

// ---------------- fused gather + GEMM + pool. One block (256 thr) per bin.
__global__ __launch_bounds__(256, 4) void k_gnn(const int* __restrict__ bin_cnt,
                                                const int* __restrict__ eb,
                                                const unsigned short* __restrict__ xb,
                                                const unsigned short* __restrict__ wt,
                                                const float* __restrict__ b_rel,
                                                const int* __restrict__ batch,
                                                int* __restrict__ g_i) {
    __shared__ int h[64], base[64], cursor[64];
    __shared__ int list[BINCAP];
    __shared__ unsigned short at[64 * 104];   // agg tile, padded row stride
    const int b = blockIdx.x, t = threadIdx.x;
    const int total = min(bin_cnt[b], BINCAP); // hardening: never read/sort OOB
    const int* ebb = eb + b * BINCAP;

    // ---- phase 1: counting sort by local node
    if (t < 64) h[t] = 0;
    __syncthreads();
    for (int i = t; i < total; i += 256) atomicAdd(&h[ebb[i] & 63], 1);
    __syncthreads();
    if (t < 64) {
        int v = h[t], s = v;
#pragma unroll
        for (int dd = 1; dd < 64; dd <<= 1) {
            int o = __shfl_up(s, dd);
            if (t >= dd) s += o;
        }
        base[t] = s - v;
        cursor[t] = s - v;
    }
    __syncthreads();
    for (int i = t; i < total; i += 256) {
        int m = ebb[i];
        int p = atomicAdd(&cursor[m & 63], 1);
        list[p] = m >> 6;
    }
    __syncthreads();

    // ---- phase 2: gather (thread = node x colgroup of 24), x4 unrolled
    {
        int node = t >> 2, cg = t & 3;
        const ushort8* xv = reinterpret_cast<const ushort8*>(xb);
        float acc[24];
#pragma unroll
        for (int j = 0; j < 24; j++) acc[j] = 0.f;
        int deg = h[node], lb = base[node];
        int e = 0;
        for (; e + 4 <= deg; e += 4) {
            int s0 = list[lb + e],     s1 = list[lb + e + 1];
            int s2 = list[lb + e + 2], s3 = list[lb + e + 3];
            const ushort8* x0 = xv + s0 * 16 + cg * 3;
            const ushort8* x1 = xv + s1 * 16 + cg * 3;
            const ushort8* x2 = xv + s2 * 16 + cg * 3;
            const ushort8* x3 = xv + s3 * 16 + cg * 3;
            ushort8 a0 = x0[0], b0 = x0[1], c0 = x0[2];
            ushort8 a1 = x1[0], b1 = x1[1], c1 = x1[2];
            ushort8 a2 = x2[0], b2 = x2[1], c2 = x2[2];
            ushort8 a3 = x3[0], b3 = x3[1], c3 = x3[2];
#pragma unroll
            for (int j = 0; j < 8; j++) {
                acc[j]      += (bf2f(a0[j]) + bf2f(a1[j])) + (bf2f(a2[j]) + bf2f(a3[j]));
                acc[8 + j]  += (bf2f(b0[j]) + bf2f(b1[j])) + (bf2f(b2[j]) + bf2f(b3[j]));
                acc[16 + j] += (bf2f(c0[j]) + bf2f(c1[j])) + (bf2f(c2[j]) + bf2f(c3[j]));
            }
        }
        for (; e < deg; e++) {
            int s0 = list[lb + e];
            const ushort8* x0 = xv + s0 * 16 + cg * 3;
            ushort8 a0 = x0[0], b0 = x0[1], c0 = x0[2];
#pragma unroll
            for (int j = 0; j < 8; j++) {
                acc[j]      += bf2f(a0[j]);
                acc[8 + j]  += bf2f(b0[j]);
                acc[16 + j] += bf2f(c0[j]);
            }
        }
        short8 r0, r1, r2;
#pragma unroll
        for (int j = 0; j < 8; j++) {
            r0[j] = (short)f2bf(acc[j]);
            r1[j] = (short)f2bf(acc[8 + j]);
            r2[j] = (short)f2bf(acc[16 + j]);
        }
        short8* ap = reinterpret_cast<short8*>(at + node * 104 + cg * 24);
        ap[0] = r0; ap[1] = r1; ap[2] = r2;
    }
    __syncthreads();

    // ---- phase 3: GEMM 64x256x192 (wave = 64-col slice)
    const int lane = t & 63;
    const int wave = t >> 6;
    const int quad = lane >> 4;
    const int l15  = lane & 15;
    const int row_base = b * 64;
    const int n0 = wave * 64;

    floatx4 C[4][4];
#pragma unroll
    for (int i = 0; i < 4; i++)
#pragma unroll
        for (int j = 0; j < 4; j++) C[i][j] = (floatx4)0.0f;

#pragma unroll
    for (int kc = 0; kc < 6; kc++) {
        short8 a4[4];
#pragma unroll
        for (int mf = 0; mf < 4; mf++) {
            if (kc < 3) {
                a4[mf] = *reinterpret_cast<const short8*>(
                    at + (mf * 16 + l15) * 104 + kc * 32 + quad * 8);
            } else {
                int r = row_base + mf * 16 + l15;
                a4[mf] = (r < N_NODES)
                    ? *reinterpret_cast<const short8*>(xb + r * XPAD + (kc - 3) * 32 + quad * 8)
                    : (short8)0;
            }
        }
        short8 b4[4];
#pragma unroll
        for (int nf = 0; nf < 4; nf++)
            b4[nf] = *reinterpret_cast<const short8*>(
                wt + (n0 + nf * 16 + l15) * 192 + kc * 32 + quad * 8);
#pragma unroll
        for (int mf = 0; mf < 4; mf++)
#pragma unroll
            for (int nf = 0; nf < 4; nf++)
                C[mf][nf] = __builtin_amdgcn_mfma_f32_16x16x32_bf16(
                    a4[mf], b4[nf], C[mf][nf], 0, 0, 0);
    }

    // ---- phase 4: bias + relu + segment-max pool
    bool fast = (row_base + 63 < N_NODES) && (batch[row_base] == batch[row_base + 63]);
    if (fast) {
        int gid = batch[row_base];
#pragma unroll
        for (int nf = 0; nf < 4; nf++) {
            float m = C[0][nf][0];
#pragma unroll
            for (int mf = 0; mf < 4; mf++)
#pragma unroll
                for (int r = 0; r < 4; r++) m = fmaxf(m, C[mf][nf][r]);
            m = fmaxf(m, __shfl_xor(m, 16));
            m = fmaxf(m, __shfl_xor(m, 32));
            if (quad == 0) {
                int n = n0 + nf * 16 + l15;
                float v = fmaxf(m + b_rel[n], 0.0f);
                atomicMax(&g_i[gid * 256 + n], __float_as_int(v));
            }
        }
    } else {
#pragma unroll
        for (int mf = 0; mf < 4; mf++) {
            int rb = row_base + mf * 16 + quad * 4;
            if (rb >= N_NODES) continue;
            bool merged = (rb + 3 < N_NODES) && (batch[rb] == batch[rb + 3]);
            if (merged) {
                int gid = batch[rb];
#pragma unroll
                for (int nf = 0; nf < 4; nf++) {
                    float m = fmaxf(fmaxf(C[mf][nf][0], C[mf][nf][1]),
                                    fmaxf(C[mf][nf][2], C[mf][nf][3]));
                    int n = n0 + nf * 16 + l15;
                    float v = fmaxf(m + b_rel[n], 0.0f);
                    atomicMax(&g_i[gid * 256 + n], __float_as_int(v));
                }
            } else {
                for (int r = 0; r < 4; r++) {
                    int rg = rb + r;
                    if (rg >= N_NODES) break;
                    int gid = batch[rg];
#pragma unroll
                    for (int nf = 0; nf < 4; nf++) {
                        int n = n0 + nf * 16 + l15;
                        float v = fmaxf(C[mf][nf][r] + b_rel[n], 0.0f);
                        atomicMax(&g_i[gid * 256 + n], __float_as_int(v));
                    }
                }
            }
        }
    }
}

// ---------------- K4: g2 = relu(g @ W1 + b1). 2 graphs x 256 outs per block.
__global__ __launch_bounds__(256) void k_mlp1(const float* __restrict__ g,
                                              const float* __restrict__ W1,
                                              const float* __restrict__ b1,
                                              float* __restrict__ g2) {
    __shared__ float sg[2 * 256];
    int m0 = (blockIdx.x >> 1) * 2;
    int nh = (blockIdx.x & 1) * 256;
    int t  = threadIdx.x;
#pragma unroll
    for (int i = 0; i < 2; i++) sg[t + i * 256] = g[m0 * 256 + t + i * 256];
    __syncthreads();
    int n = nh + t;
    float a0 = 0.f, a1 = 0.f;
#pragma unroll 4
    for (int k4 = 0; k4 < 64; k4++) {
        float4 u = reinterpret_cast<const float4*>(sg)[k4];
        float4 v = reinterpret_cast<const float4*>(sg + 256)[k4];
        int k = k4 * 4;
        float w0 = W1[(k + 0) * 512 + n];
        float w1 = W1[(k + 1) * 512 + n];
        float w2 = W1[(k + 2) * 512 + n];
        float w3 = W1[(k + 3) * 512 + n];
        a0 += u.x * w0 + u.y * w1 + u.z * w2 + u.w * w3;
        a1 += v.x * w0 + v.y * w1 + v.z * w2 + v.w * w3;
    }
    float bb = b1[n];
    g2[(m0 + 0) * 512 + n] = fmaxf(a0 + bb, 0.f);
    g2[(m0 + 1) * 512 + n] = fmaxf(a1 + bb, 0.f);
}

// ---------------- K5: out = g2 @ W2 + b2
__global__ __launch_bounds__(256) void k_mlp2(const float* __restrict__ g2,
                                              const float* __restrict__ W2,
                                              const float* __restrict__ b2,
                                              float* __restrict__ out) {
    __shared__ float sg[2 * 512];
    int m0 = blockIdx.x * 2;
    int n  = blockIdx.y * 256 + threadIdx.x;
    int t  = threadIdx.x;
#pragma unroll
    for (int i = 0; i < 4; i++) sg[t + i * 256] = g2[m0 * 512 + t + i * 256];
    __syncthreads();
    float a0 = 0.f, a1 = 0.f;
#pragma unroll 4
    for (int k4 = 0; k4 < 128; k4++) {
        float4 u = reinterpret_cast<const float4*>(sg)[k4];
        float4 v = reinterpret_cast<const float4*>(sg + 512)[k4];
        int k = k4 * 4;
        float w0 = W2[(k + 0) * 768 + n];
        float w1 = W2[(k + 1) * 768 + n];
        float w2 = W2[(k + 2) * 768 + n];
        float w3 = W2[(k + 3) * 768 + n];
        a0 += u.x * w0 + u.y * w1 + u.z * w2 + u.w * w3;
        a1 += v.x * w0 + v.y * w1 + v.z * w2 + v.w * w3;
    }
    float bb = b2[n];
    out[(m0 + 0) * 768 + n] = a0 + bb;
    out[(m0 + 1) * 768 + n] = a1 + bb;
}

extern "C" void kernel_launch(void* const* d_in, const int* in_sizes, int n_in,
                              void* d_out, int out_size, void* d_ws, size_t ws_size,
                              hipStream_t stream) {
    const float* x      = (const float*)d_in[0];
    const int*   ei     = (const int*)d_in[1];
    const int*   batch  = (const int*)d_in[2];
    const float* W_rel  = (const float*)d_in[3];
    const float* b_rel  = (const float*)d_in[4];
    const float* W_root = (const float*)d_in[5];
    const float* W1     = (const float*)d_in[6];
    const float* b1     = (const float*)d_in[7];
    const float* W2     = (const float*)d_in[8];
    const float* b2     = (const float*)d_in[9];
    float* out = (float*)d_out;

    char* ws = (char*)d_ws;
    unsigned short* xb = (unsigned short*)(ws);              // 12,800,000 (padded rows)
    float* g       = (float*)(ws + 12800000);                //    262,144
    int* bin_cnt   = (int*)  (ws + 13062144);                //      3,136 (784 ints)
    int* eb        = (int*)  (ws + 13065280);                //  4,804,608 (782*1536*4)
    float* g2      = (float*)(ws + 17869888);                //    524,288
    unsigned short* wt = (unsigned short*)(ws + 18394176);   //     98,304

    k_prep<<<2344, 256, 0, stream>>>(x, xb, W_rel, W_root, wt, g, bin_cnt);
    k_fill_bin<<<131, 256, 0, stream>>>(ei, bin_cnt, eb);
    k_gnn<<<NBINS, 256, 0, stream>>>(bin_cnt, eb, xb, wt, b_rel, batch, (int*)g);
    k_mlp1<<<256, 256, 0, stream>>>(g, W1, b1, g2);
    k_mlp2<<<dim3(128, 3), 256, 0, stream>>>(g2, W2, b2, out);
}

// Round 18
// 191.534 us; speedup vs baseline: 1.0745x; 1.0745x over previous
//
#include <hip/hip_runtime.h>

constexpr int N_NODES = 50000;
constexpr int N_EDGES = 800000;
constexpr int NBINS   = 782;     // ceil(50000/64), 64 nodes per bin
constexpr int BINCAP  = 1536;    // mean 1024, sd 32 -> +16 sigma, never overflows

typedef __attribute__((ext_vector_type(8))) short short8;
typedef __attribute__((ext_vector_type(8))) unsigned short ushort8;
typedef __attribute__((ext_vector_type(4))) float floatx4;

static __device__ __forceinline__ unsigned short f2bf(float f) {
    unsigned u = __float_as_uint(f);
    u += 0x7FFF + ((u >> 16) & 1);
    return (unsigned short)(u >> 16);
}
static __device__ __forceinline__ float bf2f(unsigned short s) {
    return __uint_as_float(((unsigned)s) << 16);
}

// ---------------- K_p: x fp32 -> bf16; W transpose->bf16; zero g and bin_cnt
__global__ __launch_bounds__(256) void k_prep(const float* __restrict__ x,
                                              unsigned short* __restrict__ xb,
                                              const float* __restrict__ Wrel,
                                              const float* __restrict__ Wroot,
                                              unsigned short* __restrict__ wt,
                                              float* __restrict__ g,
                                              int* __restrict__ bin_cnt) {
    int idx = blockIdx.x * 256 + threadIdx.x;
    if (idx < 49152) {                                  // Wt[n][k] = bf16(Wcat[k][n])
        int k = idx % 192;
        int n = idx / 192;
        float v = (k < 96) ? Wrel[k * 256 + n] : Wroot[(k - 96) * 256 + n];
        wt[idx] = f2bf(v);
    }
    if (idx < 16384) {
        reinterpret_cast<float4*>(g)[idx] = make_float4(0.f, 0.f, 0.f, 0.f);
    } else if (idx < 16384 + 196) {                     // 784 ints >= NBINS
        reinterpret_cast<int4*>(bin_cnt)[idx - 16384] = make_int4(0, 0, 0, 0);
    }
    if (idx >= N_NODES * 96 / 8) return;
    const float4* p = reinterpret_cast<const float4*>(x) + idx * 2;
    float4 u = p[0], v = p[1];
    short8 a;
    a[0] = (short)f2bf(u.x); a[1] = (short)f2bf(u.y);
    a[2] = (short)f2bf(u.z); a[3] = (short)f2bf(u.w);
    a[4] = (short)f2bf(v.x); a[5] = (short)f2bf(v.y);
    a[6] = (short)f2bf(v.z); a[7] = (short)f2bf(v.w);
    reinterpret_cast<short8*>(xb)[idx] = a;
}

// ---------------- binned fill, fixed-capacity bins (OOB-hardened)
__global__ __launch_bounds__(256) void k_fill_bin(const int* __restrict__ ei,
                                                  int* __restrict__ bin_cnt,
                                                  int* __restrict__ eb) {
    __shared__ int h[NBINS];
    __shared__ int gbase[NBINS];
    int t = threadIdx.x;
    for (int b = t; b < NBINS; b += 256) h[b] = 0;
    __syncthreads();
    int e0 = blockIdx.x * 6144;
#pragma unroll
    for (int i = 0; i < 24; i++) {
        int e = e0 + i * 256 + t;
        if (e < N_EDGES) atomicAdd(&h[ei[N_EDGES + e] >> 6], 1);
    }
    __syncthreads();
    for (int b = t; b < NBINS; b += 256) {
        int c = h[b];
        gbase[b] = c ? atomicAdd(&bin_cnt[b], c) : 0;
        h[b] = 0;
    }
    __syncthreads();
#pragma unroll
    for (int i = 0; i < 24; i++) {
        int e = e0 + i * 256 + t;
        if (e < N_EDGES) {
            int s = ei[e];
            int d = ei[N_EDGES + e];
            int bin = d >> 6;
            int p = gbase[bin] + atomicAdd(&h[bin], 1);
            if (p < BINCAP)                       // hardening: never write OOB
                eb[bin * BINCAP + p] = (s << 6) | (d & 63);
        }
    }
}

// ---------------- fused gather + GEMM + pool. One block (256 thr) per bin.
__global__ __launch_bounds__(256, 4) void k_gnn(const int* __restrict__ bin_cnt,
                                                const int* __restrict__ eb,
                                                const unsigned short* __restrict__ xb,
                                                const unsigned short* __restrict__ wt,
                                                const float* __restrict__ b_rel,
                                                const int* __restrict__ batch,
                                                int* __restrict__ g_i) {
    __shared__ int h[64], base[64], cursor[64];
    __shared__ int list[BINCAP];
    __shared__ unsigned short at[64 * 104];   // agg tile, padded row stride
    const int b = blockIdx.x, t = threadIdx.x;
    const int total = min(bin_cnt[b], BINCAP); // hardening: never read/sort OOB
    const int* ebb = eb + b * BINCAP;

    // ---- phase 1: counting sort by local node
    if (t < 64) h[t] = 0;
    __syncthreads();
    for (int i = t; i < total; i += 256) atomicAdd(&h[ebb[i] & 63], 1);
    __syncthreads();
    if (t < 64) {
        int v = h[t], s = v;
#pragma unroll
        for (int dd = 1; dd < 64; dd <<= 1) {
            int o = __shfl_up(s, dd);
            if (t >= dd) s += o;
        }
        base[t] = s - v;
        cursor[t] = s - v;
    }
    __syncthreads();
    for (int i = t; i < total; i += 256) {
        int m = ebb[i];
        int p = atomicAdd(&cursor[m & 63], 1);
        list[p] = m >> 6;
    }
    __syncthreads();

    // ---- phase 2: gather (thread = node x colgroup of 24), x4 unrolled
    {
        int node = t >> 2, cg = t & 3;
        const ushort8* xv = reinterpret_cast<const ushort8*>(xb);
        float acc[24];
#pragma unroll
        for (int j = 0; j < 24; j++) acc[j] = 0.f;
        int deg = h[node], lb = base[node];
        int e = 0;
        for (; e + 4 <= deg; e += 4) {
            int s0 = list[lb + e],     s1 = list[lb + e + 1];
            int s2 = list[lb + e + 2], s3 = list[lb + e + 3];
            const ushort8* x0 = xv + s0 * 12 + cg * 3;
            const ushort8* x1 = xv + s1 * 12 + cg * 3;
            const ushort8* x2 = xv + s2 * 12 + cg * 3;
            const ushort8* x3 = xv + s3 * 12 + cg * 3;
            ushort8 a0 = x0[0], b0 = x0[1], c0 = x0[2];
            ushort8 a1 = x1[0], b1 = x1[1], c1 = x1[2];
            ushort8 a2 = x2[0], b2 = x2[1], c2 = x2[2];
            ushort8 a3 = x3[0], b3 = x3[1], c3 = x3[2];
#pragma unroll
            for (int j = 0; j < 8; j++) {
                acc[j]      += (bf2f(a0[j]) + bf2f(a1[j])) + (bf2f(a2[j]) + bf2f(a3[j]));
                acc[8 + j]  += (bf2f(b0[j]) + bf2f(b1[j])) + (bf2f(b2[j]) + bf2f(b3[j]));
                acc[16 + j] += (bf2f(c0[j]) + bf2f(c1[j])) + (bf2f(c2[j]) + bf2f(c3[j]));
            }
        }
        for (; e < deg; e++) {
            int s0 = list[lb + e];
            const ushort8* x0 = xv + s0 * 12 + cg * 3;
            ushort8 a0 = x0[0], b0 = x0[1], c0 = x0[2];
#pragma unroll
            for (int j = 0; j < 8; j++) {
                acc[j]      += bf2f(a0[j]);
                acc[8 + j]  += bf2f(b0[j]);
                acc[16 + j] += bf2f(c0[j]);
            }
        }
        short8 r0, r1, r2;
#pragma unroll
        for (int j = 0; j < 8; j++) {
            r0[j] = (short)f2bf(acc[j]);
            r1[j] = (short)f2bf(acc[8 + j]);
            r2[j] = (short)f2bf(acc[16 + j]);
        }
        short8* ap = reinterpret_cast<short8*>(at + node * 104 + cg * 24);
        ap[0] = r0; ap[1] = r1; ap[2] = r2;
    }
    __syncthreads();

    // ---- phase 3: GEMM 64x256x192 (wave = 64-col slice)
    const int lane = t & 63;
    const int wave = t >> 6;
    const int quad = lane >> 4;
    const int l15  = lane & 15;
    const int row_base = b * 64;
    const int n0 = wave * 64;

    floatx4 C[4][4];
#pragma unroll
    for (int i = 0; i < 4; i++)
#pragma unroll
        for (int j = 0; j < 4; j++) C[i][j] = (floatx4)0.0f;

#pragma unroll
    for (int kc = 0; kc < 6; kc++) {
        short8 a4[4];
#pragma unroll
        for (int mf = 0; mf < 4; mf++) {
            if (kc < 3) {
                a4[mf] = *reinterpret_cast<const short8*>(
                    at + (mf * 16 + l15) * 104 + kc * 32 + quad * 8);
            } else {
                int r = row_base + mf * 16 + l15;
                a4[mf] = (r < N_NODES)
                    ? *reinterpret_cast<const short8*>(xb + r * 96 + (kc - 3) * 32 + quad * 8)
                    : (short8)0;
            }
        }
        short8 b4[4];
#pragma unroll
        for (int nf = 0; nf < 4; nf++)
            b4[nf] = *reinterpret_cast<const short8*>(
                wt + (n0 + nf * 16 + l15) * 192 + kc * 32 + quad * 8);
#pragma unroll
        for (int mf = 0; mf < 4; mf++)
#pragma unroll
            for (int nf = 0; nf < 4; nf++)
                C[mf][nf] = __builtin_amdgcn_mfma_f32_16x16x32_bf16(
                    a4[mf], b4[nf], C[mf][nf], 0, 0, 0);
    }

    // ---- phase 4: bias + relu + segment-max pool
    bool fast = (row_base + 63 < N_NODES) && (batch[row_base] == batch[row_base + 63]);
    if (fast) {
        int gid = batch[row_base];
#pragma unroll
        for (int nf = 0; nf < 4; nf++) {
            float m = C[0][nf][0];
#pragma unroll
            for (int mf = 0; mf < 4; mf++)
#pragma unroll
                for (int r = 0; r < 4; r++) m = fmaxf(m, C[mf][nf][r]);
            m = fmaxf(m, __shfl_xor(m, 16));
            m = fmaxf(m, __shfl_xor(m, 32));
            if (quad == 0) {
                int n = n0 + nf * 16 + l15;
                float v = fmaxf(m + b_rel[n], 0.0f);
                atomicMax(&g_i[gid * 256 + n], __float_as_int(v));
            }
        }
    } else {
#pragma unroll
        for (int mf = 0; mf < 4; mf++) {
            int rb = row_base + mf * 16 + quad * 4;
            if (rb >= N_NODES) continue;
            bool merged = (rb + 3 < N_NODES) && (batch[rb] == batch[rb + 3]);
            if (merged) {
                int gid = batch[rb];
#pragma unroll
                for (int nf = 0; nf < 4; nf++) {
                    float m = fmaxf(fmaxf(C[mf][nf][0], C[mf][nf][1]),
                                    fmaxf(C[mf][nf][2], C[mf][nf][3]));
                    int n = n0 + nf * 16 + l15;
                    float v = fmaxf(m + b_rel[n], 0.0f);
                    atomicMax(&g_i[gid * 256 + n], __float_as_int(v));
                }
            } else {
                for (int r = 0; r < 4; r++) {
                    int rg = rb + r;
                    if (rg >= N_NODES) break;
                    int gid = batch[rg];
#pragma unroll
                    for (int nf = 0; nf < 4; nf++) {
                        int n = n0 + nf * 16 + l15;
                        float v = fmaxf(C[mf][nf][r] + b_rel[n], 0.0f);
                        atomicMax(&g_i[gid * 256 + n], __float_as_int(v));
                    }
                }
            }
        }
    }
}

// ---------------- K4: g2 = relu(g @ W1 + b1). 2 graphs x 256 outs per block.
__global__ __launch_bounds__(256) void k_mlp1(const float* __restrict__ g,
                                              const float* __restrict__ W1,
                                              const float* __restrict__ b1,
                                              float* __restrict__ g2) {
    __shared__ float sg[2 * 256];
    int m0 = (blockIdx.x >> 1) * 2;
    int nh = (blockIdx.x & 1) * 256;
    int t  = threadIdx.x;
#pragma unroll
    for (int i = 0; i < 2; i++) sg[t + i * 256] = g[m0 * 256 + t + i * 256];
    __syncthreads();
    int n = nh + t;
    float a0 = 0.f, a1 = 0.f;
#pragma unroll 4
    for (int k4 = 0; k4 < 64; k4++) {
        float4 u = reinterpret_cast<const float4*>(sg)[k4];
        float4 v = reinterpret_cast<const float4*>(sg + 256)[k4];
        int k = k4 * 4;
        float w0 = W1[(k + 0) * 512 + n];
        float w1 = W1[(k + 1) * 512 + n];
        float w2 = W1[(k + 2) * 512 + n];
        float w3 = W1[(k + 3) * 512 + n];
        a0 += u.x * w0 + u.y * w1 + u.z * w2 + u.w * w3;
        a1 += v.x * w0 + v.y * w1 + v.z * w2 + v.w * w3;
    }
    float bb = b1[n];
    g2[(m0 + 0) * 512 + n] = fmaxf(a0 + bb, 0.f);
    g2[(m0 + 1) * 512 + n] = fmaxf(a1 + bb, 0.f);
}

// ---------------- K5: out = g2 @ W2 + b2
__global__ __launch_bounds__(256) void k_mlp2(const float* __restrict__ g2,
                                              const float* __restrict__ W2,
                                              const float* __restrict__ b2,
                                              float* __restrict__ out) {
    __shared__ float sg[2 * 512];
    int m0 = blockIdx.x * 2;
    int n  = blockIdx.y * 256 + threadIdx.x;
    int t  = threadIdx.x;
#pragma unroll
    for (int i = 0; i < 4; i++) sg[t + i * 256] = g2[m0 * 512 + t + i * 256];
    __syncthreads();
    float a0 = 0.f, a1 = 0.f;
#pragma unroll 4
    for (int k4 = 0; k4 < 128; k4++) {
        float4 u = reinterpret_cast<const float4*>(sg)[k4];
        float4 v = reinterpret_cast<const float4*>(sg + 512)[k4];
        int k = k4 * 4;
        float w0 = W2[(k + 0) * 768 + n];
        float w1 = W2[(k + 1) * 768 + n];
        float w2 = W2[(k + 2) * 768 + n];
        float w3 = W2[(k + 3) * 768 + n];
        a0 += u.x * w0 + u.y * w1 + u.z * w2 + u.w * w3;
        a1 += v.x * w0 + v.y * w1 + v.z * w2 + v.w * w3;
    }
    float bb = b2[n];
    out[(m0 + 0) * 768 + n] = a0 + bb;
    out[(m0 + 1) * 768 + n] = a1 + bb;
}

extern "C" void kernel_launch(void* const* d_in, const int* in_sizes, int n_in,
                              void* d_out, int out_size, void* d_ws, size_t ws_size,
                              hipStream_t stream) {
    const float* x      = (const float*)d_in[0];
    const int*   ei     = (const int*)d_in[1];
    const int*   batch  = (const int*)d_in[2];
    const float* W_rel  = (const float*)d_in[3];
    const float* b_rel  = (const float*)d_in[4];
    const float* W_root = (const float*)d_in[5];
    const float* W1     = (const float*)d_in[6];
    const float* b1     = (const float*)d_in[7];
    const float* W2     = (const float*)d_in[8];
    const float* b2     = (const float*)d_in[9];
    float* out = (float*)d_out;

    char* ws = (char*)d_ws;
    unsigned short* xb = (unsigned short*)(ws);              //  9,600,000
    float* g       = (float*)(ws + 9600000);                 //    262,144
    int* bin_cnt   = (int*)  (ws + 9862144);                 //      3,136 (784 ints)
    int* eb        = (int*)  (ws + 9865280);                 //  4,804,608 (782*1536*4)
    float* g2      = (float*)(ws + 14669888);                //    524,288
    unsigned short* wt = (unsigned short*)(ws + 15194176);   //     98,304

    k_prep<<<2344, 256, 0, stream>>>(x, xb, W_rel, W_root, wt, g, bin_cnt);
    k_fill_bin<<<131, 256, 0, stream>>>(ei, bin_cnt, eb);
    k_gnn<<<NBINS, 256, 0, stream>>>(bin_cnt, eb, xb, wt, b_rel, batch, (int*)g);
    k_mlp1<<<256, 256, 0, stream>>>(g, W1, b1, g2);
    k_mlp2<<<dim3(128, 3), 256, 0, stream>>>(g2, W2, b2, out);
}